// Round 3
// baseline (898.521 us; speedup 1.0000x reference)
//
#include <hip/hip_runtime.h>
#include <hip/hip_bf16.h>

#define NUM_HEADS 16
#define DM 1024
#define DEPTH 64
#define BB 4
#define SS 1024
#define SL 1023            // S-1
#define M_ROWS (BB*SL)     // 4092
#define M_PAD 4096

typedef __attribute__((ext_vector_type(8))) short short8;
typedef __attribute__((ext_vector_type(4))) float floatx4;

__device__ inline unsigned short f2bf(float f) {
  __hip_bfloat16 hb = __float2bfloat16(f);
  return *reinterpret_cast<unsigned short*>(&hb);
}
__device__ inline float bf2fu(unsigned short u) {
  union { unsigned int i; float f; } x; x.i = ((unsigned int)u) << 16; return x.f;
}
__device__ inline short8 ld_frag(const unsigned short* p) {
  return *reinterpret_cast<const short8*>(p);
}

// ---- prep: WT[n][k] = bf16(W[k][n]) for Wv (z=0) and Wd (z=1) --------------
__global__ __launch_bounds__(256) void prep_wt(
    const float* __restrict__ Wv, const float* __restrict__ Wd,
    unsigned short* __restrict__ WvT, unsigned short* __restrict__ WdT)
{
  const float* W = blockIdx.z ? Wd : Wv;
  unsigned short* WT = blockIdx.z ? WdT : WvT;
  __shared__ unsigned short tile[64][66];
  int n0 = blockIdx.x * 64, k0 = blockIdx.y * 64;
  int c = threadIdx.x & 63, g = threadIdx.x >> 6;
  #pragma unroll
  for (int i = 0; i < 16; i++) {
    int kk = g * 16 + i;
    tile[kk][c] = f2bf(W[(size_t)(k0 + kk) * DM + n0 + c]);
  }
  __syncthreads();
  #pragma unroll
  for (int i = 0; i < 16; i++) {
    int nn = g * 16 + i;
    WT[(size_t)(n0 + nn) * DM + k0 + c] = tile[c][nn];
  }
}

// ---- GEMM: C[M x 1024] = A[M x 1024] @ B + bias; B given as BT[n][k] bf16 --
// 128x128 block tile, BK=32, 4 waves (2x2), wave tile 64x64 (4x4 MFMA 16x16x32)
template <bool A_FP32, bool OUT_BF16>
__global__ __launch_bounds__(256) void gemm_bias(
    const void* __restrict__ Av, const unsigned short* __restrict__ BT,
    const float* __restrict__ bias, void* __restrict__ Cv, int M)
{
  __shared__ unsigned short Ash[128][32];
  __shared__ unsigned short Bsh[128][32];
  const int tid = threadIdx.x;
  const int w = tid >> 6, lane = tid & 63, q4 = lane >> 4, l16 = lane & 15;
  const int wm = w >> 1, wn = w & 1;
  const int rb = blockIdx.y * 128;
  const int cb = blockIdx.x * 128;
  // lane-linear staging: thread t covers rows r0 and 64+r0, 16B chunk kc0
  const int r0 = tid >> 2;
  const int kc0 = (tid & 3) * 8;   // u16 offset

  floatx4 acc[4][4];
  #pragma unroll
  for (int i = 0; i < 4; i++)
    #pragma unroll
    for (int j = 0; j < 4; j++) acc[i][j] = (floatx4){0.f,0.f,0.f,0.f};

  const int ra0 = min(rb + r0, M - 1);
  const int ra1 = min(rb + 64 + r0, M - 1);

  for (int k0 = 0; k0 < DM; k0 += 32) {
    __syncthreads();
    if (A_FP32) {
      const float* g0 = (const float*)Av + (size_t)ra0 * DM + k0 + kc0;
      const float* g1 = (const float*)Av + (size_t)ra1 * DM + k0 + kc0;
      float4 x0 = *(const float4*)g0, x1 = *(const float4*)(g0 + 4);
      float4 y0 = *(const float4*)g1, y1 = *(const float4*)(g1 + 4);
      unsigned short t0[8] = {f2bf(x0.x),f2bf(x0.y),f2bf(x0.z),f2bf(x0.w),
                              f2bf(x1.x),f2bf(x1.y),f2bf(x1.z),f2bf(x1.w)};
      unsigned short t1[8] = {f2bf(y0.x),f2bf(y0.y),f2bf(y0.z),f2bf(y0.w),
                              f2bf(y1.x),f2bf(y1.y),f2bf(y1.z),f2bf(y1.w)};
      *(uint4*)&Ash[r0][kc0]      = *(uint4*)t0;
      *(uint4*)&Ash[64 + r0][kc0] = *(uint4*)t1;
    } else {
      *(uint4*)&Ash[r0][kc0]      = *(const uint4*)((const unsigned short*)Av + (size_t)ra0 * DM + k0 + kc0);
      *(uint4*)&Ash[64 + r0][kc0] = *(const uint4*)((const unsigned short*)Av + (size_t)ra1 * DM + k0 + kc0);
    }
    *(uint4*)&Bsh[r0][kc0]      = *(const uint4*)(BT + (size_t)(cb + r0) * DM + k0 + kc0);
    *(uint4*)&Bsh[64 + r0][kc0] = *(const uint4*)(BT + (size_t)(cb + 64 + r0) * DM + k0 + kc0);
    __syncthreads();

    short8 af[4], bfr[4];
    #pragma unroll
    for (int i = 0; i < 4; i++) af[i]  = ld_frag(&Ash[wm*64 + i*16 + l16][q4*8]);
    #pragma unroll
    for (int j = 0; j < 4; j++) bfr[j] = ld_frag(&Bsh[wn*64 + j*16 + l16][q4*8]);
    #pragma unroll
    for (int j = 0; j < 4; j++)
      #pragma unroll
      for (int i = 0; i < 4; i++)
        acc[i][j] = __builtin_amdgcn_mfma_f32_16x16x32_bf16(af[i], bfr[j], acc[i][j], 0, 0, 0);
  }

  #pragma unroll
  for (int j = 0; j < 4; j++) {
    int col = cb + wn*64 + j*16 + l16;
    float bb = bias[col];
    #pragma unroll
    for (int i = 0; i < 4; i++) {
      #pragma unroll
      for (int r = 0; r < 4; r++) {
        int m = rb + wm*64 + i*16 + q4*4 + r;
        if (m < M) {
          float val = acc[i][j][r] + bb;
          if (OUT_BF16) ((unsigned short*)Cv)[(size_t)m * DM + col] = f2bf(val);
          else          ((float*)Cv)[(size_t)m * DM + col] = val;
        }
      }
    }
  }
}

// ---- Attention: single K-sweep, P strip resident in LDS --------------------
// grid (16 q-tiles, 16 heads, 4 batch), block 256 = 4 waves, wave owns 16 q rows
__global__ __launch_bounds__(256) void attn_kernel(
    const float* __restrict__ Q, const float* __restrict__ Kg,
    const float* __restrict__ Mask, const unsigned short* __restrict__ VV,
    float* __restrict__ Att, unsigned short* __restrict__ Out2)
{
  const int qt = blockIdx.x, h = blockIdx.y, b = blockIdx.z;
  const int tid = threadIdx.x;
  const int w = tid >> 6, lane = tid & 63, q4 = lane >> 4, l16 = lane & 15;
  const int qi0 = qt * 64;
  const int qb = w * 16;

  __shared__ unsigned short psh[64][1032];   // unnormalized P, bf16 (132 KB)
  __shared__ unsigned short qsh[64][72];     // Q tile
  __shared__ unsigned short kvsh[64][72];    // K tiles, then V^T tiles

  // stage Q (row qi reads q[b][qi+1][h*64+d])
  {
    int qr = tid >> 2, d0 = (tid & 3) * 16;
    int qi = qi0 + qr;
    unsigned short tmp[16];
    if (qi < SL) {
      const float* src = Q + ((size_t)b * SS + qi + 1) * DM + h * DEPTH + d0;
      #pragma unroll
      for (int j = 0; j < 16; j += 4) {
        float4 f = *(const float4*)(src + j);
        tmp[j]=f2bf(f.x); tmp[j+1]=f2bf(f.y); tmp[j+2]=f2bf(f.z); tmp[j+3]=f2bf(f.w);
      }
    } else {
      #pragma unroll
      for (int j = 0; j < 16; j++) tmp[j] = 0;
    }
    *(uint4*)&qsh[qr][d0]     = *(uint4*)&tmp[0];
    *(uint4*)&qsh[qr][d0 + 8] = *(uint4*)&tmp[8];
  }
  __syncthreads();
  const short8 qf0 = ld_frag(&qsh[qb + l16][q4*8]);
  const short8 qf1 = ld_frag(&qsh[qb + l16][32 + q4*8]);

  float rsv[4] = {0.f, 0.f, 0.f, 0.f};

  // ---- single sweep: S -> p -> psh + rowsum ----
  for (int kt = 0; kt < 16; kt++) {
    __syncthreads();
    {
      int kr = tid >> 2, d0 = (tid & 3) * 16;
      int kj = kt * 64 + kr;
      unsigned short tmp[16];
      if (kj < SL) {
        const float* src = Kg + ((size_t)b * SS + kj) * DM + h * DEPTH + d0;
        #pragma unroll
        for (int j = 0; j < 16; j += 4) {
          float4 f = *(const float4*)(src + j);
          tmp[j]=f2bf(f.x); tmp[j+1]=f2bf(f.y); tmp[j+2]=f2bf(f.z); tmp[j+3]=f2bf(f.w);
        }
      } else {
        #pragma unroll
        for (int j = 0; j < 16; j++) tmp[j] = 0;
      }
      *(uint4*)&kvsh[kr][d0]     = *(uint4*)&tmp[0];
      *(uint4*)&kvsh[kr][d0 + 8] = *(uint4*)&tmp[8];
    }
    __syncthreads();

    #pragma unroll
    for (int nt = 0; nt < 4; nt++) {
      floatx4 s = (floatx4){0.f,0.f,0.f,0.f};
      s = __builtin_amdgcn_mfma_f32_16x16x32_bf16(qf0, ld_frag(&kvsh[nt*16 + l16][q4*8]), s, 0,0,0);
      s = __builtin_amdgcn_mfma_f32_16x16x32_bf16(qf1, ld_frag(&kvsh[nt*16 + l16][32 + q4*8]), s, 0,0,0);
      int kj = kt * 64 + nt * 16 + l16;
      bool kv = kj < SL;
      int qi_b = qi0 + qb + q4 * 4;
      const float* mp = Mask + ((size_t)b * SL + qi_b) * SL + kj;
      #pragma unroll
      for (int r = 0; r < 4; r++) {
        bool qv = (qi_b + r) < SL;
        float mval = (kv && qv) ? mp[(size_t)r * SL] : 0.f;
        float sv = fmaxf(s[r] * 0.125f, 0.f) + mval * (-1e9f);
        float p = kv ? __expf(sv) : 0.f;
        unsigned short u = f2bf(p);
        psh[qb + q4*4 + r][kt*64 + nt*16 + l16] = u;
        rsv[r] += bf2fu(u);
      }
    }
  }

  float inv4[4];
  #pragma unroll
  for (int r = 0; r < 4; r++) {
    float s = rsv[r];
    s += __shfl_xor(s, 1, 64); s += __shfl_xor(s, 2, 64);
    s += __shfl_xor(s, 4, 64); s += __shfl_xor(s, 8, 64);
    inv4[r] = 1.f / s;
  }

  // ---- normalize + att write (wave-private rows; no barrier needed) ----
  #pragma unroll
  for (int rr = 0; rr < 16; rr++) {
    int row = qb + rr;
    int qi = qi0 + row;
    if (qi < SL) {
      float iv = __shfl(inv4[rr & 3], (rr >> 2) * 16, 64);
      float* arow = Att + (((size_t)(b * NUM_HEADS + h)) * SL + qi) * SL;
      for (int col = lane; col < SL; col += 64)
        arow[col] = bf2fu(psh[row][col]) * iv;
    }
  }

  // ---- PV from LDS P strip ----
  floatx4 oacc[4];
  #pragma unroll
  for (int i = 0; i < 4; i++) oacc[i] = (floatx4){0.f,0.f,0.f,0.f};

  for (int kt = 0; kt < 16; kt++) {
    __syncthreads();
    {
      int d = tid & 63, k16 = (tid >> 6) * 16;
      unsigned short tmp[16];
      #pragma unroll
      for (int j = 0; j < 16; j++) {
        int kj = kt * 64 + k16 + j;
        tmp[j] = (kj < SL) ? VV[((size_t)b * SL + kj) * DM + h * DEPTH + d] : (unsigned short)0;
      }
      *(uint4*)&kvsh[d][k16]     = *(uint4*)&tmp[0];
      *(uint4*)&kvsh[d][k16 + 8] = *(uint4*)&tmp[8];
    }
    __syncthreads();
    short8 pa0 = ld_frag(&psh[qb + l16][kt*64 + q4*8]);
    short8 pa1 = ld_frag(&psh[qb + l16][kt*64 + 32 + q4*8]);
    #pragma unroll
    for (int nt2 = 0; nt2 < 4; nt2++) {
      oacc[nt2] = __builtin_amdgcn_mfma_f32_16x16x32_bf16(pa0, ld_frag(&kvsh[nt2*16 + l16][q4*8]), oacc[nt2], 0,0,0);
      oacc[nt2] = __builtin_amdgcn_mfma_f32_16x16x32_bf16(pa1, ld_frag(&kvsh[nt2*16 + l16][32 + q4*8]), oacc[nt2], 0,0,0);
    }
  }

  #pragma unroll
  for (int nt2 = 0; nt2 < 4; nt2++) {
    #pragma unroll
    for (int r = 0; r < 4; r++) {
      int qi = qi0 + qb + q4*4 + r;
      if (qi < SL)
        Out2[((size_t)b * SL + qi) * DM + h * DEPTH + nt2*16 + l16] = f2bf(oacc[nt2][r] * inv4[r]);
    }
  }
}

extern "C" void kernel_launch(void* const* d_in, const int* in_sizes, int n_in,
                              void* d_out, int out_size, void* d_ws, size_t ws_size,
                              hipStream_t stream) {
  const float* v    = (const float*)d_in[0];
  const float* k    = (const float*)d_in[1];
  const float* q    = (const float*)d_in[2];
  const float* mask = (const float*)d_in[3];
  const float* Wv   = (const float*)d_in[4];
  const float* bv   = (const float*)d_in[5];
  const float* Wd   = (const float*)d_in[6];
  const float* bd   = (const float*)d_in[7];

  float* out = (float*)d_out;                                  // (4,1023,1024) fp32
  float* att = out + (size_t)M_ROWS * DM;                      // (4,16,1023,1023) fp32

  unsigned short* vv   = (unsigned short*)d_ws;                // bf16 [M_PAD][DM]
  unsigned short* out2 = vv + (size_t)M_PAD * DM;              // bf16 [M_PAD][DM]
  unsigned short* WvT  = out2 + (size_t)M_PAD * DM;            // bf16 [DM][DM]
  unsigned short* WdT  = WvT + (size_t)DM * DM;                // bf16 [DM][DM]

  prep_wt<<<dim3(DM/64, DM/64, 2), 256, 0, stream>>>(Wv, Wd, WvT, WdT);
  // vv = v @ Wv + bv (fp32 A, bf16 out)
  gemm_bias<true, true><<<dim3(DM/128, M_PAD/128), 256, 0, stream>>>(
      (const void*)v, WvT, bv, (void*)vv, M_ROWS);
  // attention: att (fp32, d_out) + out2 (bf16, ws)
  attn_kernel<<<dim3(16, NUM_HEADS, BB), 256, 0, stream>>>(q, k, mask, vv, att, out2);
  // out = out2 @ Wd + bd (bf16 A, fp32 out)
  gemm_bias<false, false><<<dim3(DM/128, M_PAD/128), 256, 0, stream>>>(
      (const void*)out2, WdT, bd, (void*)out, M_ROWS);
}